// Round 1
// baseline (730.844 us; speedup 1.0000x reference)
//
#include <hip/hip_runtime.h>
#include <math.h>

#define DIM 64

__device__ __forceinline__ float silu_f(float x) {
    return x / (1.0f + __expf(-x));
}

// ---------------- Kernel 1: node projections Q, K and scalar gate ----------------
// Q[n,d] = bq[d] + sum_k x[n,k] Wq[k,d]   (same for K)
// gate[n] = x[n,:]·u + c0,  u[k] = Wv[k,:]·wF,  c0 = bv·wF + bF
__global__ __launch_bounds__(256) void k_proj(
    const float* __restrict__ x,
    const float* __restrict__ Wq, const float* __restrict__ bq,
    const float* __restrict__ Wk, const float* __restrict__ bk,
    const float* __restrict__ Wv, const float* __restrict__ bv,
    const float* __restrict__ wF, const float* __restrict__ bF,
    float* __restrict__ Q, float* __restrict__ Kp,
    float* __restrict__ gate, int nNodes)
{
    __shared__ float sWqT[64][68];  // transposed, padded: lane d reads row d as b128
    __shared__ float sWkT[64][68];
    __shared__ float sx[64][68];
    __shared__ float su[64];
    __shared__ float sc0;

    int tid = threadIdx.x;
    int d = tid & 63;
    int sub = tid >> 6;   // wave id 0..3

    for (int r = sub; r < 64; r += 4) {
        sWqT[d][r] = Wq[r * 64 + d];
        sWkT[d][r] = Wk[r * 64 + d];
    }
    if (tid < 64) {
        float acc = 0.f;
        for (int k = 0; k < 64; ++k) acc += Wv[tid * 64 + k] * wF[k];
        su[tid] = acc;
    }
    if (tid == 0) {
        float acc = bF[0];
        for (int k = 0; k < 64; ++k) acc += bv[k] * wF[k];
        sc0 = acc;
    }
    int node0 = blockIdx.x * 64;
    for (int r = sub; r < 64; r += 4) {
        int g = node0 + r;
        sx[r][d] = (g < nNodes) ? x[(size_t)g * 64 + d] : 0.f;
    }
    __syncthreads();

    float bqv = bq[d], bkv = bk[d];
    for (int t = 0; t < 16; ++t) {
        int n = sub * 16 + t;         // wave-uniform node index
        int g = node0 + n;
        if (g >= nNodes) continue;    // wave-uniform branch
        float accQ = bqv, accK = bkv;
        #pragma unroll
        for (int k = 0; k < 64; ++k) {
            float xv = sx[n][k];      // broadcast
            accQ += xv * sWqT[d][k];  // contiguous per lane -> b128
            accK += xv * sWkT[d][k];
        }
        float pg = sx[n][d] * su[d];
        #pragma unroll
        for (int off = 32; off; off >>= 1) pg += __shfl_xor(pg, off, 64);
        Q[(size_t)g * 64 + d] = accQ;
        Kp[(size_t)g * 64 + d] = accK;
        if (d == 0) gate[g] = pg + sc0;
    }
}

// ---------------- Kernel 2: per-edge MLP bias + QK score; exp + denom ----------------
__global__ __launch_bounds__(256) void k_edge1(
    const int* __restrict__ ei, const int* __restrict__ ej,
    const float* __restrict__ Q, const float* __restrict__ Kp,
    const float* __restrict__ edge_vec,
    const float* __restrict__ W1, const float* __restrict__ b1,
    const float* __restrict__ W2, const float* __restrict__ b2,
    const float* __restrict__ W3, const float* __restrict__ b3,
    float* __restrict__ exbuf, float* __restrict__ denom, int nEdges)
{
    __shared__ float sW2[64][64];   // row-major [k][d]; b128 broadcast on [k][dd..dd+3]
    __shared__ float sW1[4][64];
    __shared__ float sb1[64], sb2[64], sW3[64];
    __shared__ float sb3;

    int tid = threadIdx.x;
    int d = tid & 63, sub = tid >> 6;
    for (int r = sub; r < 64; r += 4) sW2[r][d] = W2[r * 64 + d];
    if (sub == 0) sb1[d] = b1[d];
    else if (sub == 1) sb2[d] = b2[d];
    else if (sub == 2) sW3[d] = W3[d];
    else {
        #pragma unroll
        for (int c = 0; c < 4; ++c) sW1[c][d] = W1[c * 64 + d];
    }
    if (tid == 0) sb3 = b3[0];
    __syncthreads();

    int e = blockIdx.x * 256 + tid;
    if (e >= nEdges) return;

    int i = ei[e], j = ej[e];
    float vx = edge_vec[(size_t)e * 3 + 0];
    float vy = edge_vec[(size_t)e * 3 + 1];
    float vz = edge_vec[(size_t)e * 3 + 2];
    float len = sqrtf(vx * vx + vy * vy + vz * vz);

    // h1 = silu(attr @ W1 + b1), kept in registers (64 VGPRs)
    float h1[64];
    #pragma unroll
    for (int k = 0; k < 64; ++k) {
        float s = sb1[k] + vx * sW1[0][k] + vy * sW1[1][k] + vz * sW1[2][k] + len * sW1[3][k];
        h1[k] = silu_f(s);
    }

    // bias = silu(h1 @ W2 + b2) @ W3 + b3, d-blocked by 4 for b128 LDS reads
    float bias = sb3;
    for (int dd = 0; dd < 64; dd += 4) {
        float s0 = sb2[dd + 0], s1 = sb2[dd + 1], s2 = sb2[dd + 2], s3 = sb2[dd + 3];
        #pragma unroll
        for (int k = 0; k < 64; ++k) {
            float h = h1[k];
            s0 += h * sW2[k][dd + 0];
            s1 += h * sW2[k][dd + 1];
            s2 += h * sW2[k][dd + 2];
            s3 += h * sW2[k][dd + 3];
        }
        bias += silu_f(s0) * sW3[dd + 0] + silu_f(s1) * sW3[dd + 1]
              + silu_f(s2) * sW3[dd + 2] + silu_f(s3) * sW3[dd + 3];
    }

    // score = Q[j]·K[i] / 8 + bias
    const float* qr = Q + (size_t)j * 64;
    const float* kr = Kp + (size_t)i * 64;
    float dot = 0.f;
    #pragma unroll
    for (int k = 0; k < 64; ++k) dot += qr[k] * kr[k];

    float score = dot * 0.125f + bias;
    float ev = __expf(score);        // max-free softmax: scores bounded ~±15
    exbuf[e] = ev;
    atomicAdd(&denom[j], ev);
}

// ---------------- Kernel 3: alpha-weighted scatter of gate * edge_vec ----------------
__global__ __launch_bounds__(256) void k_edge2(
    const int* __restrict__ ei, const int* __restrict__ ej,
    const float* __restrict__ exbuf, const float* __restrict__ denom,
    const float* __restrict__ gate, const float* __restrict__ edge_vec,
    float* __restrict__ out, int nEdges)
{
    int e = blockIdx.x * 256 + threadIdx.x;
    if (e >= nEdges) return;
    int i = ei[e], j = ej[e];
    float alpha = exbuf[e] / (denom[j] + 1e-16f);
    float g = alpha * gate[i];
    float vx = edge_vec[(size_t)e * 3 + 0];
    float vy = edge_vec[(size_t)e * 3 + 1];
    float vz = edge_vec[(size_t)e * 3 + 2];
    atomicAdd(&out[(size_t)j * 3 + 0], g * vx);
    atomicAdd(&out[(size_t)j * 3 + 1], g * vy);
    atomicAdd(&out[(size_t)j * 3 + 2], g * vz);
}

extern "C" void kernel_launch(void* const* d_in, const int* in_sizes, int n_in,
                              void* d_out, int out_size, void* d_ws, size_t ws_size,
                              hipStream_t stream)
{
    const float* x        = (const float*)d_in[0];
    const float* edge_vec = (const float*)d_in[1];
    const float* Wq = (const float*)d_in[2];
    const float* bq = (const float*)d_in[3];
    const float* Wk = (const float*)d_in[4];
    const float* bk = (const float*)d_in[5];
    const float* Wv = (const float*)d_in[6];
    const float* bv = (const float*)d_in[7];
    const float* W1 = (const float*)d_in[8];
    const float* b1 = (const float*)d_in[9];
    const float* W2 = (const float*)d_in[10];
    const float* b2 = (const float*)d_in[11];
    const float* W3 = (const float*)d_in[12];
    const float* b3 = (const float*)d_in[13];
    const float* wF = (const float*)d_in[14];
    const float* bF = (const float*)d_in[15];
    const int*   eidx = (const int*)d_in[16];

    int nNodes = in_sizes[0] / DIM;
    int nEdges = in_sizes[16] / 2;
    const int* ei = eidx;            // edge_index[0]
    const int* ej = eidx + nEdges;   // edge_index[1]

    float* ws    = (float*)d_ws;
    float* Q     = ws;
    float* Kp    = Q + (size_t)nNodes * DIM;
    float* gate  = Kp + (size_t)nNodes * DIM;
    float* denom = gate + nNodes;
    float* exbuf = denom + nNodes;

    float* out = (float*)d_out;
    hipMemsetAsync(out, 0, (size_t)out_size * sizeof(float), stream);
    hipMemsetAsync(denom, 0, (size_t)nNodes * sizeof(float), stream);

    int nb1 = (nNodes + 63) / 64;
    k_proj<<<nb1, 256, 0, stream>>>(x, Wq, bq, Wk, bk, Wv, bv, wF, bF, Q, Kp, gate, nNodes);

    int nb2 = (nEdges + 255) / 256;
    k_edge1<<<nb2, 256, 0, stream>>>(ei, ej, Q, Kp, edge_vec, W1, b1, W2, b2, W3, b3,
                                     exbuf, denom, nEdges);
    k_edge2<<<nb2, 256, 0, stream>>>(ei, ej, exbuf, denom, gate, edge_vec, out, nEdges);
}